// Round 3
// baseline (84.464 us; speedup 1.0000x reference)
//
#include <hip/hip_runtime.h>

#define BATCH 2048
#define ODIM 64
#define IDIM 64
#define MDIM 32
#define OUT_STRIDE (BATCH * ODIM)

static constexpr float LOG2E = 1.4426950408889634f;

#if __has_builtin(__builtin_amdgcn_exp2f)
#define EXP2F(x) __builtin_amdgcn_exp2f(x)
#else
#define EXP2F(x) exp2f(x)
#endif

typedef float v2f __attribute__((ext_vector_type(2)));

// Rotate/permute-add within 16-lane DPP rows (all rows in parallel).
// ctrl must be a compile-time constant -> template parameter.
template <int CTRL>
__device__ __forceinline__ float dpp_add(float v) {
    int s = __builtin_amdgcn_update_dpp(0, __builtin_bit_cast(int, v),
                                        CTRL, 0xF, 0xF, true);
    return v + __builtin_bit_cast(float, s);
}

// Lane = i (64 i = 64 lanes). Coefficients for the lane's (o,i) live in
// VGPRs as v2f splats (128 regs) -> the 64-FMA Horner inner loop is pure
// register pk-FMA, zero LDS. Previous versions paid ~21 us/CU of LDS
// return-bandwidth on "broadcast" coefficient reads (1024 B delivered per
// wave-uniform ds_read_b128, LDS unit shared by 4 SIMDs).
//
// Block = (o, 256 b), 8 waves; wave owns 32 b as 16 pk-pairs. Per pair:
// compute em/ev per (b,i), clamp per-cell, then i-sum via per-wave LDS
// bounce (4x ds_write_b32 conflict-free + 1 ds_read_b128) + quad-add +
// 4 DPP rotate-adds; row leads store straight to out. No barriers in loop.
__global__ __launch_bounds__(512, 2) void gpkan_fused_kernel(
    const float* __restrict__ x, const float* __restrict__ z,
    const float* __restrict__ q_mu, const float* __restrict__ q_log_var,
    const float* __restrict__ log_scale, const float* __restrict__ log_variance,
    float* __restrict__ out)
{
    const int o     = blockIdx.x & (ODIM - 1);
    const int btile = blockIdx.x >> 6;                 // 0..7 (256 b each)
    const int tid   = threadIdx.x;
    const int lane  = tid & 63;                        // = i
    const int wave  = tid >> 6;                        // 0..7

    __shared__ float4 lds_c[IDIM][16];                 // 16 KB, k rotated by +i
    __shared__ float4 lds_aux[IDIM];                   // 1 KB
    __shared__ __align__(16) float red[8][4][64];      // 8 KB, per-wave slices

    // ---------------- Phase 1: coefficient build (rotated store) ----------
    #pragma unroll
    for (int rep = 0; rep < 2; ++rep) {
        const int q  = tid + rep * 512;                // quad id 0..1023
        const int i  = q >> 4;
        const int k  = q & 15;
        const int oi = o * IDIM + i;
        const int g  = oi * MDIM + 2 * k;

        const float ls = log_scale[oi];
        const float lv = log_variance[oi];
        const float ell   = fmaxf(expf(ls), 0.1f);
        const float ell2  = ell * ell;
        const float vk    = fmaxf(expf(lv), 1e-5f);
        const float denom = ell2 + 1e-6f;              // x_var == EPS_XVAR
        const float A = vk * sqrtf(ell2 / denom);
        const float a = -0.5f * LOG2E / denom;         // base-2 exponent scale

        const float2 qm = *(const float2*)(q_mu + g);
        const float2 ql = *(const float2*)(q_log_var + g);
        const float2 zm = *(const float2*)(z + g);
        const float qv0 = fmaxf(expf(ql.x), 1e-5f);
        const float qv1 = fmaxf(expf(ql.y), 1e-5f);
        const float w0  = EXP2F(a * zm.x * zm.x);
        const float w1  = EXP2F(a * zm.y * zm.y);

        float4 c;
        c.x = A * qm.x * w0;                           // c1[2k]   (Pe coeff)
        c.y = A * A * (qv0 + qm.x * qm.x) * w0 * w0;   // c2[2k]   (Qe coeff)
        c.z = A * qm.y * w1;                           // c1[2k+1] (Po coeff)
        c.w = A * A * (qv1 + qm.y * qm.y) * w1 * w1;   // c2[2k+1] (Qo coeff)
        lds_c[i][(k + i) & 15] = c;                    // rotate: kills the
                                                       // 64-lane stride-256B
                                                       // conflict on pull
        if (k == 0)
            lds_aux[i] = make_float4(a, -2.0f * a * zm.x,
                                     -2.0f * a * (zm.y - zm.x), 0.0f);
    }
    __syncthreads();

    // ---------------- Coefficient pull: lane's own i -> v2f splats --------
    v2f C1e[16], C1o[16], C2e[16], C2o[16];            // 128 VGPRs
    #pragma unroll
    for (int k = 0; k < 16; ++k) {
        const float4 q = lds_c[lane][(k + lane) & 15];
        C1e[k] = (v2f){q.x, q.x};
        C2e[k] = (v2f){q.y, q.y};
        C1o[k] = (v2f){q.z, q.z};
        C2o[k] = (v2f){q.w, q.w};
    }
    const float4 Ax = lds_aux[lane];
    const v2f e1 = {Ax.x, Ax.x}, e2 = {Ax.y, Ax.y}, rc = {Ax.z, Ax.z};

    const int bbase = btile * 256 + wave * 32;
    float* redw = &red[wave][0][0];                    // wave-private slice
    const int v = lane >> 4, j = lane & 15;            // reduce-row roles

    // ---------------- Phase 2: b-loop, 2 chunks x 8 pk-pairs --------------
    #pragma unroll
    for (int c = 0; c < 2; ++c) {
        v2f xv[8];
        #pragma unroll
        for (int p = 0; p < 8; ++p) {                  // coalesced, L2-resident
            const int b0 = bbase + (c * 8 + p) * 2;
            xv[p].x = x[(size_t)b0 * IDIM + lane];
            xv[p].y = x[(size_t)(b0 + 1) * IDIM + lane];
        }
        #pragma unroll
        for (int p = 0; p < 8; ++p) {
            const int b0 = bbase + (c * 8 + p) * 2;
            const v2f x2 = xv[p];

            v2f t = __builtin_elementwise_fma(e1, x2, e2) * x2;
            v2f Eb, rr;
            Eb.x = EXP2F(t.x); Eb.y = EXP2F(t.y);
            const v2f ur = rc * x2;
            rr.x = EXP2F(ur.x); rr.y = EXP2F(ur.y);
            const v2f s = rr * rr;                     // P arg
            const v2f u = s * s;                       // Q arg

            v2f Pe = {0.f, 0.f}, Po = {0.f, 0.f};
            v2f Qe = {0.f, 0.f}, Qo = {0.f, 0.f};
            #pragma unroll
            for (int k = 15; k >= 0; --k) {            // all-VGPR pk-FMA
                Pe = __builtin_elementwise_fma(Pe, s, C1e[k]);
                Po = __builtin_elementwise_fma(Po, s, C1o[k]);
                Qe = __builtin_elementwise_fma(Qe, u, C2e[k]);
                Qo = __builtin_elementwise_fma(Qo, u, C2o[k]);
            }
            const v2f P = __builtin_elementwise_fma(rr, Po, Pe);
            const v2f Q = __builtin_elementwise_fma(s,  Qo, Qe);

            const v2f em = Eb * P;
            const v2f ev = (Eb * Eb) * Q;
            const v2f eps = {1e-6f, 1e-6f};
            const v2f d   = __builtin_elementwise_fma(-em, em, ev);
            const v2f evc = __builtin_elementwise_max(d, eps);  // per-cell clamp

            // i-sum: wave-private LDS bounce (writes bank i%32: 2-way, free)
            redw[0 * 64 + lane] = em.x;
            redw[1 * 64 + lane] = evc.x;
            redw[2 * 64 + lane] = em.y;
            redw[3 * 64 + lane] = evc.y;
            asm volatile("s_waitcnt lgkmcnt(0)" ::: "memory");
            const float4 qd = *(const float4*)&redw[v * 64 + j * 4];
            float partial = (qd.x + qd.y) + (qd.z + qd.w);
            // 16-lane row reduce: xor1, xor2, ror4, ror8 (rows = planes)
            partial = dpp_add<0xB1>(partial);          // quad_perm [1,0,3,2]
            partial = dpp_add<0x4E>(partial);          // quad_perm [2,3,0,1]
            partial = dpp_add<0x124>(partial);         // row_ror:4
            partial = dpp_add<0x128>(partial);         // row_ror:8
            if (j == 0) {                              // planes: em0,ev0,em1,ev1
                const int b = b0 + (v >> 1);
                out[(size_t)(v & 1) * OUT_STRIDE + (size_t)b * ODIM + o] = partial;
            }
        }
    }
}

extern "C" void kernel_launch(void* const* d_in, const int* in_sizes, int n_in,
                              void* d_out, int out_size, void* d_ws, size_t ws_size,
                              hipStream_t stream) {
    const float* x            = (const float*)d_in[0];
    const float* z            = (const float*)d_in[1];
    const float* q_mu         = (const float*)d_in[2];
    const float* q_log_var    = (const float*)d_in[3];
    const float* log_scale    = (const float*)d_in[4];
    const float* log_variance = (const float*)d_in[5];
    float* out = (float*)d_out;

    (void)d_ws; (void)ws_size;  // poison fill is unconditional; ws unused

    gpkan_fused_kernel<<<dim3((BATCH / 256) * ODIM), dim3(512), 0, stream>>>(
        x, z, q_mu, q_log_var, log_scale, log_variance, out);
}